// Round 4
// baseline (229.667 us; speedup 1.0000x reference)
//
#include <hip/hip_runtime.h>

typedef _Float16 v8h __attribute__((ext_vector_type(8)));
typedef _Float16 v4h __attribute__((ext_vector_type(4)));
typedef _Float16 v2h __attribute__((ext_vector_type(2)));
typedef float v4f __attribute__((ext_vector_type(4)));

#define NB 64
#define CI 96
#define CE 576
#define CO 96
#define HW 784
#define SEC 144

#if defined(__has_builtin)
#if __has_builtin(__builtin_amdgcn_fdot2)
#define HAVE_FDOT2 1
#endif
#endif

__device__ __forceinline__ float fdot2(v2h a, v2h b, float c) {
#ifdef HAVE_FDOT2
  return __builtin_amdgcn_fdot2(a, b, c, false);
#else
  return (float)a[0] * (float)b[0] + ((float)a[1] * (float)b[1] + c);
#endif
}

// ---------------- K0: convert GEMM weights to fp16 (integers +-127, exact) ----
__global__ __launch_bounds__(256) void k0_cvt_w(const float* __restrict__ w_exp,
                                                const float* __restrict__ w_proj,
                                                _Float16* __restrict__ w_exp_h,
                                                _Float16* __restrict__ w_proj_h) {
  int i = blockIdx.x * 256 + threadIdx.x;
  if (i < CE * CI) {                 // 55296 == CE*CI == CO*CE
    w_exp_h[i]  = (_Float16)w_exp[i];
    w_proj_h[i] = (_Float16)w_proj[i];
  }
}

// ---------------- K1: expand 1x1 + hardswish + requant -> e_s fp16 [n][c][hw] --
// LDS holds x-tile in MFMA-B-fragment packed layout: X[s][t][lane][8j], tile
// padded 512->520 halves so t-stride (260 dw) == 4 mod 32 -> staging writes ~2-way.
// Fragment reads are consecutive-16B ds_read_b128 (conflict-free).
__global__ __launch_bounds__(384) void k1_expand(const float* __restrict__ x,
                                                 const _Float16* __restrict__ w_exp_h,
                                                 const float* __restrict__ b_exp,
                                                 _Float16* __restrict__ e_s) {
  __shared__ _Float16 xf[3 * 7 * 520];   // 21840 B
  const int tid = threadIdx.x;
  const int n   = blockIdx.z;
  const int co0 = blockIdx.y * 96;
  const int hw0 = blockIdx.x * 112;

#pragma unroll
  for (int it = 0; it < 7; ++it) {       // 7*384 == CI*28
    int idx = it * 384 + tid;
    int c = idx / 28, seg = idx % 28;
    const float4 v = *(const float4*)&x[(n * CI + c) * HW + hw0 + seg * 4];
    int s = c >> 5, q = (c >> 3) & 3, j = c & 7;
    int t = seg >> 2, l0 = (seg & 3) * 4;
    int base = (s * 7 + t) * 520 + (q * 16 + l0) * 8 + j;
    xf[base]      = (_Float16)(v.x - 128.0f);
    xf[base + 8]  = (_Float16)(v.y - 128.0f);
    xf[base + 16] = (_Float16)(v.z - 128.0f);
    xf[base + 24] = (_Float16)(v.w - 128.0f);
  }
  __syncthreads();

  const int wv = tid >> 6, lane = tid & 63;
  const int l15 = lane & 15, q = lane >> 4;

  const _Float16* wrow = &w_exp_h[(co0 + wv * 16 + l15) * CI + q * 8];
  v8h a0 = *(const v8h*)(wrow);
  v8h a1 = *(const v8h*)(wrow + 32);
  v8h a2 = *(const v8h*)(wrow + 64);

  v4f acc[7];
#pragma unroll
  for (int t = 0; t < 7; ++t) acc[t] = (v4f){0.f, 0.f, 0.f, 0.f};

#pragma unroll
  for (int t = 0; t < 7; ++t) {
    v8h b0 = *(const v8h*)&xf[(0 * 7 + t) * 520 + lane * 8];
    v8h b1 = *(const v8h*)&xf[(1 * 7 + t) * 520 + lane * 8];
    v8h b2 = *(const v8h*)&xf[(2 * 7 + t) * 520 + lane * 8];
    acc[t] = __builtin_amdgcn_mfma_f32_16x16x32_f16(a0, b0, acc[t], 0, 0, 0);
    acc[t] = __builtin_amdgcn_mfma_f32_16x16x32_f16(a1, b1, acc[t], 0, 0, 0);
    acc[t] = __builtin_amdgcn_mfma_f32_16x16x32_f16(a2, b2, acc[t], 0, 0, 0);
  }

  float bia[4];
#pragma unroll
  for (int r = 0; r < 4; ++r) bia[r] = b_exp[co0 + wv * 16 + q * 4 + r];

#pragma unroll
  for (int t = 0; t < 7; ++t) {
#pragma unroll
    for (int r = 0; r < 4; ++r) {
      int co = co0 + wv * 16 + q * 4 + r;
      int hw = hw0 + t * 16 + l15;
      float deq = (acc[t][r] + bia[r]) * 5.0e-4f;            // S_IN * W_SCALE
      float cl  = fminf(fmaxf(deq + 3.0f, 0.0f), 6.0f);
      float hs  = deq * cl * (1.0f / 6.0f);
      float ev  = fminf(fmaxf(hs * 25.0f, -128.0f), 127.0f); // (e - 128)
      e_s[(n * CE + co) * HW + hw] = (_Float16)ev;
    }
  }
}

// ---------------- K2: depthwise 5x5 + hardswish + requant + pool sums ---------
// block: (c-group of 8, n); 256 thr. Output written in k-packed layout
// d_t[n][cg][hw][8] via LDS transpose ([784][9] pad -> ~2-way conflicts,
// coalesced 16B global writeout).
__global__ __launch_bounds__(256, 4) void k2_dw(const _Float16* __restrict__ e_s,
                                                const float* __restrict__ w_dw,
                                                const float* __restrict__ b_dw,
                                                _Float16* __restrict__ d_t,
                                                float* __restrict__ d_sums) {
  __shared__ _Float16 e_lds[8][32][36];   // row stride 72B = 18 banks (gcd 2 -> free)
  __shared__ _Float16 w_pairs[8][5][8];   // [c][dy][w0,w1,w2,w3, w1,w2,w3,w4]
  __shared__ _Float16 d_tile[784 * 9];    // [hw][c], stride 9 halves (~2-way)
  const int tid = threadIdx.x;
  const int n = blockIdx.y;
  const int c0 = blockIdx.x * 8;

  // zero the halo (whole input buffer)
  {
    unsigned long long* z = (unsigned long long*)&e_lds[0][0][0];
    for (int idx = tid; idx < 8 * 32 * 36 * 2 / 8; idx += 256) z[idx] = 0ull;
  }
  // stage duplicated weight pairs (f16, exact for int weights)
  for (int idx = tid; idx < 320; idx += 256) {
    int c = idx / 40, r = idx % 40, dy = r / 8, k = r % 8;
    int tap = (k < 4) ? k : (k - 3);
    w_pairs[c][dy][k] = (_Float16)w_dw[(c0 + c) * 25 + dy * 5 + tap];
  }
  __syncthreads();
  // stage interior rows: 8 ch * 28 rows * 7 aligned b64 chunks
  for (int idx = tid; idx < 1568; idx += 256) {
    int c = idx / 196, r = idx % 196, y = r / 7, j = r % 7;
    v4h v = *(const v4h*)&e_s[(n * CE + c0 + c) * HW + y * 28 + j * 4];
    *(v4h*)&e_lds[c][2 + y][4 + j * 4] = v;
  }
  __syncthreads();

  const int c = tid >> 5, l = tid & 31;
  // hoist weights into registers
  v2h W01[5], W23[5], W12[5], W34[5];
  float W0s[5], W4s[5];
#pragma unroll
  for (int dy = 0; dy < 5; ++dy) {
    W01[dy] = *(const v2h*)&w_pairs[c][dy][0];
    W23[dy] = *(const v2h*)&w_pairs[c][dy][2];
    W12[dy] = *(const v2h*)&w_pairs[c][dy][4];
    W34[dy] = *(const v2h*)&w_pairs[c][dy][6];
    W0s[dy] = (float)W01[dy][0];
    W4s[dy] = (float)W34[dy][1];
  }
  const float bc = b_dw[c0 + c];

  float csum = 0.0f;
  if (l < 28) {
    const int y = l;   // output row; input rows y-2..y+2 -> LDS rows y..y+4
    v2h P0[5], P1[5], P2[5], P3[5];
#pragma unroll
    for (int dy = 0; dy < 5; ++dy) {
      const _Float16* row = &e_lds[c][y + dy][0];
      P0[dy] = *(const v2h*)(row + 2);
      P1[dy] = *(const v2h*)(row + 4);
      P2[dy] = *(const v2h*)(row + 6);
      P3[dy] = *(const v2h*)(row + 8);
    }
#pragma unroll
    for (int x0 = 0; x0 < 28; x0 += 4) {
      float o0 = bc, o1 = bc, o2 = bc, o3 = bc;
#pragma unroll
      for (int dy = 0; dy < 5; ++dy) {
        o0 = fdot2(P0[dy], W01[dy], o0);
        o0 = fdot2(P1[dy], W23[dy], o0);
        o0 += (float)P2[dy][0] * W4s[dy];
        o1 += (float)P0[dy][1] * W0s[dy];
        o1 = fdot2(P1[dy], W12[dy], o1);
        o1 = fdot2(P2[dy], W34[dy], o1);
        o2 = fdot2(P1[dy], W01[dy], o2);
        o2 = fdot2(P2[dy], W23[dy], o2);
        o2 += (float)P3[dy][0] * W4s[dy];
        o3 += (float)P1[dy][1] * W0s[dy];
        o3 = fdot2(P2[dy], W12[dy], o3);
        o3 = fdot2(P3[dy], W34[dy], o3);
      }
      float oo[4] = {o0, o1, o2, o3};
#pragma unroll
      for (int i = 0; i < 4; ++i) {
        float deq = oo[i] * 4.0e-4f;            // S1 * W_SCALE
        float cl  = fminf(fmaxf(deq + 3.0f, 0.0f), 6.0f);
        float hs  = deq * cl * (1.0f / 6.0f);
        float dvv = fminf(fmaxf(hs * 25.0f, -128.0f), 127.0f); // (d - 128)
        d_tile[(y * 28 + x0 + i) * 9 + c] = (_Float16)dvv;
        csum += dvv;
      }
      if (x0 < 24) {
#pragma unroll
        for (int dy = 0; dy < 5; ++dy) {
          const _Float16* row = &e_lds[c][y + dy][0];
          P0[dy] = P2[dy];
          P1[dy] = P3[dy];
          P2[dy] = *(const v2h*)(row + x0 + 10);
          P3[dy] = *(const v2h*)(row + x0 + 12);
        }
      }
    }
  }
#pragma unroll
  for (int m = 16; m >= 1; m >>= 1) csum += __shfl_xor(csum, m);
  if (l == 0) d_sums[n * CE + c0 + c] = csum;

  __syncthreads();
  // coalesced writeout: thread -> hw, 16B per thread, consecutive
  const size_t obase = ((size_t)n * 72 + (c0 >> 3)) * 784;
  for (int hw = tid; hw < 784; hw += 256) {
    v8h o;
#pragma unroll
    for (int j = 0; j < 8; ++j) o[j] = d_tile[hw * 9 + j];
    *(v8h*)&d_t[(obase + hw) * 8] = o;
  }
}

// ---------------- K3a: SE fc1 — one wave per (n, o) dot of length 576 ---------
__global__ __launch_bounds__(256) void k3a_fc1(const float* __restrict__ d_sums,
                                               const float* __restrict__ w_se1,
                                               const float* __restrict__ b_se1,
                                               float* __restrict__ g1) {
  const int tid = threadIdx.x;
  const int wv = tid >> 6, lane = tid & 63;
  const int n = blockIdx.y;
  const int o = blockIdx.x * 4 + wv;       // 144 outputs
  const float* wrow = &w_se1[o * CE];
  const float* srow = &d_sums[n * CE];
  float p = 0.f;
#pragma unroll
  for (int s = 0; s < 9; ++s) {
    int cc = lane + s * 64;
    p += wrow[cc] * srow[cc];
  }
#pragma unroll
  for (int m = 32; m >= 1; m >>= 1) p += __shfl_xor(p, m);
  if (lane == 0) {
    // pooled-z = d_sums/784 (d_t already stores d-128)
    float deq = (p * (1.0f / 784.0f) + b_se1[o]) * 4.0e-4f;  // S2 * W_SCALE
    g1[n * SEC + o] = fminf(fmaxf(deq * 33.3333333f + 128.0f, 0.0f), 255.0f) - 128.0f;
  }
}

// ---------------- K3b: SE fc2 + hardsigmoid -> f16 gate table -----------------
__global__ __launch_bounds__(256) void k3b_fc2(const float* __restrict__ g1,
                                               const float* __restrict__ w_se2,
                                               const float* __restrict__ b_se2,
                                               _Float16* __restrict__ g2h) {
  const int tid = threadIdx.x;
  const int wv = tid >> 6, lane = tid & 63;
  const int n = blockIdx.y;
  const int o = blockIdx.x * 4 + wv;       // 576 outputs
  const float* wrow = &w_se2[o * SEC];
  const float* grow = &g1[n * SEC];
  float p = wrow[lane] * grow[lane] + wrow[lane + 64] * grow[lane + 64];
  if (lane < 16) p += wrow[lane + 128] * grow[lane + 128];
#pragma unroll
  for (int m = 32; m >= 1; m >>= 1) p += __shfl_xor(p, m);
  if (lane == 0) {
    float deq = (p + b_se2[o]) * 3.0e-4f;  // S_SE1 * W_SCALE
    g2h[n * CE + o] =
        (_Float16)(fminf(fmaxf(deq + 3.0f, 0.0f), 6.0f) * (1.0f / 6.0f)); // hardsigmoid
  }
}

// ---------------- K4: gated project 1x1 + residual add -> out fp32 -----------
// No LDS, no barriers: B-fragment = one coalesced b128 load from k-packed d_t,
// gate applied with v_pk_mul_f16. block: (t-tile of 16 hw, n); 6 waves = M=96.
__global__ __launch_bounds__(384) void k4_proj(const _Float16* __restrict__ d_t,
                                               const _Float16* __restrict__ g2h,
                                               const _Float16* __restrict__ w_proj_h,
                                               const float* __restrict__ b_proj,
                                               const float* __restrict__ x,
                                               float* __restrict__ out) {
  const int tid = threadIdx.x;
  const int n = blockIdx.y;
  const int hw0 = blockIdx.x * 16;
  const int wv = tid >> 6, lane = tid & 63;
  const int l15 = lane & 15, q = lane >> 4;

  v4f acc = (v4f){0.f, 0.f, 0.f, 0.f};
  const _Float16* dbase = d_t + (((size_t)n * 72 + q) * 784 + hw0 + l15) * 8;
  const _Float16* abase = &w_proj_h[(wv * 16 + l15) * CE + q * 8];
  const _Float16* gbase = &g2h[(size_t)n * CE + q * 8];

#pragma unroll 3
  for (int ks = 0; ks < 18; ++ks) {
    v8h b = *(const v8h*)(dbase + (size_t)ks * (4 * 784 * 8));
    v8h a = *(const v8h*)(abase + ks * 32);
    v8h g = *(const v8h*)(gbase + ks * 32);
    b = b * g;   // 4x v_pk_mul_f16
    acc = __builtin_amdgcn_mfma_f32_16x16x32_f16(a, b, acc, 0, 0, 0);
  }

#pragma unroll
  for (int r = 0; r < 4; ++r) {
    int co = wv * 16 + q * 4 + r;
    int hw = hw0 + l15;
    float p = fminf(fmaxf((acc[r] + b_proj[co]) * 4.0e-4f * 20.0f + 128.0f, 0.0f), 255.0f);
    float xv = x[(n * CO + co) * HW + hw];
    float o = (xv - 128.0f) * 0.8333333333f + (p - 128.0f) * 0.8333333333f + 128.0f;
    out[(n * CO + co) * HW + hw] = fminf(fmaxf(o, 0.0f), 255.0f);
  }
}

extern "C" void kernel_launch(void* const* d_in, const int* in_sizes, int n_in,
                              void* d_out, int out_size, void* d_ws, size_t ws_size,
                              hipStream_t stream) {
  const float* x      = (const float*)d_in[0];
  const float* w_exp  = (const float*)d_in[1];
  const float* b_exp  = (const float*)d_in[2];
  const float* w_dw   = (const float*)d_in[3];
  const float* b_dw   = (const float*)d_in[4];
  const float* w_se1  = (const float*)d_in[5];
  const float* b_se1  = (const float*)d_in[6];
  const float* w_se2  = (const float*)d_in[7];
  const float* b_se2  = (const float*)d_in[8];
  const float* w_proj = (const float*)d_in[9];
  const float* b_proj = (const float*)d_in[10];
  float* out = (float*)d_out;

  char* ws = (char*)d_ws;
  const size_t SZ_W  = (size_t)CE * CI * 2;            // 110592 B
  const size_t SZ_ED = (size_t)NB * CE * HW * 2;       // 57802752 B
  const size_t SZ_S  = (size_t)NB * CE * 4;            // 147456 B
  _Float16* w_exp_h  = (_Float16*)(ws);
  _Float16* w_proj_h = (_Float16*)(ws + SZ_W);
  _Float16* e_s      = (_Float16*)(ws + 2 * SZ_W);
  _Float16* d_t      = (_Float16*)(ws + 2 * SZ_W + SZ_ED);     // [n][72][784][8]
  float*    d_sums   = (float*)   (ws + 2 * SZ_W + 2 * SZ_ED);
  float*    g1       = (float*)   (ws + 2 * SZ_W + 2 * SZ_ED + SZ_S);
  _Float16* g2h      = (_Float16*)(ws + 2 * SZ_W + 2 * SZ_ED + 2 * SZ_S);
  // total ws use: ~116.2 MB

  k0_cvt_w<<<(CE * CI + 255) / 256, 256, 0, stream>>>(w_exp, w_proj, w_exp_h, w_proj_h);
  k1_expand<<<dim3(7, 6, NB), 384, 0, stream>>>(x, w_exp_h, b_exp, e_s);
  k2_dw<<<dim3(72, NB), 256, 0, stream>>>(e_s, w_dw, b_dw, d_t, d_sums);
  k3a_fc1<<<dim3(36, NB), 256, 0, stream>>>(d_sums, w_se1, b_se1, g1);
  k3b_fc2<<<dim3(144, NB), 256, 0, stream>>>(g1, w_se2, b_se2, g2h);
  k4_proj<<<dim3(49, NB), 384, 0, stream>>>(d_t, g2h, w_proj_h, b_proj, x, out);
}

// Round 5
// 197.690 us; speedup vs baseline: 1.1618x; 1.1618x over previous
//
#include <hip/hip_runtime.h>

typedef _Float16 v8h __attribute__((ext_vector_type(8)));
typedef _Float16 v4h __attribute__((ext_vector_type(4)));
typedef _Float16 v2h __attribute__((ext_vector_type(2)));
typedef float v4f __attribute__((ext_vector_type(4)));

#define NB 64
#define CI 96
#define CE 576
#define CO 96
#define HW 784
#define SEC 144

#if defined(__has_builtin)
#if __has_builtin(__builtin_amdgcn_fdot2)
#define HAVE_FDOT2 1
#endif
#endif

__device__ __forceinline__ float fdot2(v2h a, v2h b, float c) {
#ifdef HAVE_FDOT2
  return __builtin_amdgcn_fdot2(a, b, c, false);
#else
  return (float)a[0] * (float)b[0] + ((float)a[1] * (float)b[1] + c);
#endif
}

// ---------------- K0: convert GEMM weights to fp16 (integers +-127, exact) ----
__global__ __launch_bounds__(256) void k0_cvt_w(const float* __restrict__ w_exp,
                                                const float* __restrict__ w_proj,
                                                _Float16* __restrict__ w_exp_h,
                                                _Float16* __restrict__ w_proj_h) {
  int i = blockIdx.x * 256 + threadIdx.x;
  if (i < CE * CI) {                 // 55296 == CE*CI == CO*CE
    w_exp_h[i]  = (_Float16)w_exp[i];
    w_proj_h[i] = (_Float16)w_proj[i];
  }
}

// ---------------- K1: expand 1x1 + hardswish + requant -> e_s fp16 [n][c][hw] --
// LDS holds x-tile in MFMA-B-fragment packed layout: X[s][t][lane][8j], tile
// padded 512->520 halves so t-stride (260 dw) == 4 mod 32 -> staging writes ~2-way.
// Fragment reads are consecutive-16B ds_read_b128 (conflict-free).
__global__ __launch_bounds__(384) void k1_expand(const float* __restrict__ x,
                                                 const _Float16* __restrict__ w_exp_h,
                                                 const float* __restrict__ b_exp,
                                                 _Float16* __restrict__ e_s) {
  __shared__ _Float16 xf[3 * 7 * 520];   // 21840 B
  const int tid = threadIdx.x;
  const int n   = blockIdx.z;
  const int co0 = blockIdx.y * 96;
  const int hw0 = blockIdx.x * 112;

#pragma unroll
  for (int it = 0; it < 7; ++it) {       // 7*384 == CI*28
    int idx = it * 384 + tid;
    int c = idx / 28, seg = idx % 28;
    const float4 v = *(const float4*)&x[(n * CI + c) * HW + hw0 + seg * 4];
    int s = c >> 5, q = (c >> 3) & 3, j = c & 7;
    int t = seg >> 2, l0 = (seg & 3) * 4;
    int base = (s * 7 + t) * 520 + (q * 16 + l0) * 8 + j;
    xf[base]      = (_Float16)(v.x - 128.0f);
    xf[base + 8]  = (_Float16)(v.y - 128.0f);
    xf[base + 16] = (_Float16)(v.z - 128.0f);
    xf[base + 24] = (_Float16)(v.w - 128.0f);
  }
  __syncthreads();

  const int wv = tid >> 6, lane = tid & 63;
  const int l15 = lane & 15, q = lane >> 4;

  const _Float16* wrow = &w_exp_h[(co0 + wv * 16 + l15) * CI + q * 8];
  v8h a0 = *(const v8h*)(wrow);
  v8h a1 = *(const v8h*)(wrow + 32);
  v8h a2 = *(const v8h*)(wrow + 64);

  v4f acc[7];
#pragma unroll
  for (int t = 0; t < 7; ++t) acc[t] = (v4f){0.f, 0.f, 0.f, 0.f};

#pragma unroll
  for (int t = 0; t < 7; ++t) {
    v8h b0 = *(const v8h*)&xf[(0 * 7 + t) * 520 + lane * 8];
    v8h b1 = *(const v8h*)&xf[(1 * 7 + t) * 520 + lane * 8];
    v8h b2 = *(const v8h*)&xf[(2 * 7 + t) * 520 + lane * 8];
    acc[t] = __builtin_amdgcn_mfma_f32_16x16x32_f16(a0, b0, acc[t], 0, 0, 0);
    acc[t] = __builtin_amdgcn_mfma_f32_16x16x32_f16(a1, b1, acc[t], 0, 0, 0);
    acc[t] = __builtin_amdgcn_mfma_f32_16x16x32_f16(a2, b2, acc[t], 0, 0, 0);
  }

  float bia[4];
#pragma unroll
  for (int r = 0; r < 4; ++r) bia[r] = b_exp[co0 + wv * 16 + q * 4 + r];

#pragma unroll
  for (int t = 0; t < 7; ++t) {
#pragma unroll
    for (int r = 0; r < 4; ++r) {
      int co = co0 + wv * 16 + q * 4 + r;
      int hw = hw0 + t * 16 + l15;
      float deq = (acc[t][r] + bia[r]) * 5.0e-4f;            // S_IN * W_SCALE
      float cl  = fminf(fmaxf(deq + 3.0f, 0.0f), 6.0f);
      float hs  = deq * cl * (1.0f / 6.0f);
      float ev  = fminf(fmaxf(hs * 25.0f, -128.0f), 127.0f); // (e - 128)
      e_s[(n * CE + co) * HW + hw] = (_Float16)ev;
    }
  }
}

// ---------------- K2: depthwise 5x5 + hardswish + requant + pool sums ---------
// block: (c-group of 8, n); 256 thr. Output written in k-packed layout
// d_t[n][cg][hw][8] via LDS transpose ([784][9] pad -> ~2-way conflicts,
// coalesced 16B global writeout).
__global__ __launch_bounds__(256, 4) void k2_dw(const _Float16* __restrict__ e_s,
                                                const float* __restrict__ w_dw,
                                                const float* __restrict__ b_dw,
                                                _Float16* __restrict__ d_t,
                                                float* __restrict__ d_sums) {
  __shared__ _Float16 e_lds[8][32][36];   // row stride 72B = 18 banks (gcd 2 -> free)
  __shared__ _Float16 w_pairs[8][5][8];   // [c][dy][w0,w1,w2,w3, w1,w2,w3,w4]
  __shared__ _Float16 d_tile[784 * 9];    // [hw][c], stride 9 halves (~2-way)
  const int tid = threadIdx.x;
  const int n = blockIdx.y;
  const int c0 = blockIdx.x * 8;

  // zero the halo (whole input buffer)
  {
    unsigned long long* z = (unsigned long long*)&e_lds[0][0][0];
    for (int idx = tid; idx < 8 * 32 * 36 * 2 / 8; idx += 256) z[idx] = 0ull;
  }
  // stage duplicated weight pairs (f16, exact for int weights)
  for (int idx = tid; idx < 320; idx += 256) {
    int c = idx / 40, r = idx % 40, dy = r / 8, k = r % 8;
    int tap = (k < 4) ? k : (k - 3);
    w_pairs[c][dy][k] = (_Float16)w_dw[(c0 + c) * 25 + dy * 5 + tap];
  }
  __syncthreads();
  // stage interior rows: 8 ch * 28 rows * 7 aligned b64 chunks
  for (int idx = tid; idx < 1568; idx += 256) {
    int c = idx / 196, r = idx % 196, y = r / 7, j = r % 7;
    v4h v = *(const v4h*)&e_s[(n * CE + c0 + c) * HW + y * 28 + j * 4];
    *(v4h*)&e_lds[c][2 + y][4 + j * 4] = v;
  }
  __syncthreads();

  const int c = tid >> 5, l = tid & 31;
  // hoist weights into registers
  v2h W01[5], W23[5], W12[5], W34[5];
  float W0s[5], W4s[5];
#pragma unroll
  for (int dy = 0; dy < 5; ++dy) {
    W01[dy] = *(const v2h*)&w_pairs[c][dy][0];
    W23[dy] = *(const v2h*)&w_pairs[c][dy][2];
    W12[dy] = *(const v2h*)&w_pairs[c][dy][4];
    W34[dy] = *(const v2h*)&w_pairs[c][dy][6];
    W0s[dy] = (float)W01[dy][0];
    W4s[dy] = (float)W34[dy][1];
  }
  const float bc = b_dw[c0 + c];

  float csum = 0.0f;
  if (l < 28) {
    const int y = l;   // output row; input rows y-2..y+2 -> LDS rows y..y+4
    v2h P0[5], P1[5], P2[5], P3[5];
#pragma unroll
    for (int dy = 0; dy < 5; ++dy) {
      const _Float16* row = &e_lds[c][y + dy][0];
      P0[dy] = *(const v2h*)(row + 2);
      P1[dy] = *(const v2h*)(row + 4);
      P2[dy] = *(const v2h*)(row + 6);
      P3[dy] = *(const v2h*)(row + 8);
    }
#pragma unroll
    for (int x0 = 0; x0 < 28; x0 += 4) {
      float o0 = bc, o1 = bc, o2 = bc, o3 = bc;
#pragma unroll
      for (int dy = 0; dy < 5; ++dy) {
        o0 = fdot2(P0[dy], W01[dy], o0);
        o0 = fdot2(P1[dy], W23[dy], o0);
        o0 += (float)P2[dy][0] * W4s[dy];
        o1 += (float)P0[dy][1] * W0s[dy];
        o1 = fdot2(P1[dy], W12[dy], o1);
        o1 = fdot2(P2[dy], W34[dy], o1);
        o2 = fdot2(P1[dy], W01[dy], o2);
        o2 = fdot2(P2[dy], W23[dy], o2);
        o2 += (float)P3[dy][0] * W4s[dy];
        o3 += (float)P1[dy][1] * W0s[dy];
        o3 = fdot2(P2[dy], W12[dy], o3);
        o3 = fdot2(P3[dy], W34[dy], o3);
      }
      float oo[4] = {o0, o1, o2, o3};
#pragma unroll
      for (int i = 0; i < 4; ++i) {
        float deq = oo[i] * 4.0e-4f;            // S1 * W_SCALE
        float cl  = fminf(fmaxf(deq + 3.0f, 0.0f), 6.0f);
        float hs  = deq * cl * (1.0f / 6.0f);
        float dvv = fminf(fmaxf(hs * 25.0f, -128.0f), 127.0f); // (d - 128)
        d_tile[(y * 28 + x0 + i) * 9 + c] = (_Float16)dvv;
        csum += dvv;
      }
      if (x0 < 24) {
#pragma unroll
        for (int dy = 0; dy < 5; ++dy) {
          const _Float16* row = &e_lds[c][y + dy][0];
          P0[dy] = P2[dy];
          P1[dy] = P3[dy];
          P2[dy] = *(const v2h*)(row + x0 + 10);
          P3[dy] = *(const v2h*)(row + x0 + 12);
        }
      }
    }
  }
#pragma unroll
  for (int m = 16; m >= 1; m >>= 1) csum += __shfl_xor(csum, m);
  if (l == 0) d_sums[n * CE + c0 + c] = csum;

  __syncthreads();
  // coalesced writeout: thread -> hw, 16B per thread, consecutive
  const size_t obase = ((size_t)n * 72 + (c0 >> 3)) * 784;
  for (int hw = tid; hw < 784; hw += 256) {
    v8h o;
#pragma unroll
    for (int j = 0; j < 8; ++j) o[j] = d_tile[hw * 9 + j];
    *(v8h*)&d_t[(obase + hw) * 8] = o;
  }
}

// ---------------- K3a: SE fc1 — one wave per (n, o) dot of length 576 ---------
__global__ __launch_bounds__(256) void k3a_fc1(const float* __restrict__ d_sums,
                                               const float* __restrict__ w_se1,
                                               const float* __restrict__ b_se1,
                                               float* __restrict__ g1) {
  const int tid = threadIdx.x;
  const int wv = tid >> 6, lane = tid & 63;
  const int n = blockIdx.y;
  const int o = blockIdx.x * 4 + wv;       // 144 outputs
  const float* wrow = &w_se1[o * CE];
  const float* srow = &d_sums[n * CE];
  float p = 0.f;
#pragma unroll
  for (int s = 0; s < 9; ++s) {
    int cc = lane + s * 64;
    p += wrow[cc] * srow[cc];
  }
#pragma unroll
  for (int m = 32; m >= 1; m >>= 1) p += __shfl_xor(p, m);
  if (lane == 0) {
    // pooled-z = d_sums/784 (d_t already stores d-128)
    float deq = (p * (1.0f / 784.0f) + b_se1[o]) * 4.0e-4f;  // S2 * W_SCALE
    g1[n * SEC + o] = fminf(fmaxf(deq * 33.3333333f + 128.0f, 0.0f), 255.0f) - 128.0f;
  }
}

// ---------------- K3b: SE fc2 + hardsigmoid -> f16 gate table -----------------
__global__ __launch_bounds__(256) void k3b_fc2(const float* __restrict__ g1,
                                               const float* __restrict__ w_se2,
                                               const float* __restrict__ b_se2,
                                               _Float16* __restrict__ g2h) {
  const int tid = threadIdx.x;
  const int wv = tid >> 6, lane = tid & 63;
  const int n = blockIdx.y;
  const int o = blockIdx.x * 4 + wv;       // 576 outputs
  const float* wrow = &w_se2[o * SEC];
  const float* grow = &g1[n * SEC];
  float p = wrow[lane] * grow[lane] + wrow[lane + 64] * grow[lane + 64];
  if (lane < 16) p += wrow[lane + 128] * grow[lane + 128];
#pragma unroll
  for (int m = 32; m >= 1; m >>= 1) p += __shfl_xor(p, m);
  if (lane == 0) {
    float deq = (p + b_se2[o]) * 3.0e-4f;  // S_SE1 * W_SCALE
    g2h[n * CE + o] =
        (_Float16)(fminf(fmaxf(deq + 3.0f, 0.0f), 6.0f) * (1.0f / 6.0f)); // hardsigmoid
  }
}

// ---------------- K4: gated project 1x1 + residual add -> out fp32 -----------
// No LDS/barriers, 7 independent accumulators per wave for load ILP.
// B = coalesced b128 from k-packed d_t; gate folded into the A fragment
// (A and B share k-fragment indexing), so 4 pk_mul per ks serve 7 MFMAs.
__global__ __launch_bounds__(384) void k4_proj(const _Float16* __restrict__ d_t,
                                               const _Float16* __restrict__ g2h,
                                               const _Float16* __restrict__ w_proj_h,
                                               const float* __restrict__ b_proj,
                                               const float* __restrict__ x,
                                               float* __restrict__ out) {
  const int tid = threadIdx.x;
  const int n = blockIdx.y;
  const int hw0 = blockIdx.x * 112;
  const int wv = tid >> 6, lane = tid & 63;
  const int l15 = lane & 15, q = lane >> 4;

  v4f acc[7];
#pragma unroll
  for (int t = 0; t < 7; ++t) acc[t] = (v4f){0.f, 0.f, 0.f, 0.f};

  const _Float16* dbase = d_t + (((size_t)n * 72 + q) * 784 + hw0 + l15) * 8;
  const _Float16* abase = &w_proj_h[(wv * 16 + l15) * CE + q * 8];
  const _Float16* gbase = &g2h[(size_t)n * CE + q * 8];

  for (int ks = 0; ks < 18; ++ks) {
    v8h a = *(const v8h*)(abase + ks * 32);
    v8h g = *(const v8h*)(gbase + ks * 32);
    v8h ag = a * g;   // 4x v_pk_mul_f16, shared across the 7 MFMAs
    const _Float16* dk = dbase + (size_t)ks * (4 * 784 * 8);
#pragma unroll
    for (int t = 0; t < 7; ++t) {
      v8h b = *(const v8h*)(dk + t * (16 * 8));
      acc[t] = __builtin_amdgcn_mfma_f32_16x16x32_f16(ag, b, acc[t], 0, 0, 0);
    }
  }

  float bia[4];
#pragma unroll
  for (int r = 0; r < 4; ++r) bia[r] = b_proj[wv * 16 + q * 4 + r];

#pragma unroll
  for (int t = 0; t < 7; ++t) {
#pragma unroll
    for (int r = 0; r < 4; ++r) {
      int co = wv * 16 + q * 4 + r;
      int hw = hw0 + t * 16 + l15;
      float p = fminf(fmaxf((acc[t][r] + bia[r]) * 4.0e-4f * 20.0f + 128.0f, 0.0f), 255.0f);
      float xv = x[(n * CO + co) * HW + hw];
      float o = (xv - 128.0f) * 0.8333333333f + (p - 128.0f) * 0.8333333333f + 128.0f;
      out[(n * CO + co) * HW + hw] = fminf(fmaxf(o, 0.0f), 255.0f);
    }
  }
}

extern "C" void kernel_launch(void* const* d_in, const int* in_sizes, int n_in,
                              void* d_out, int out_size, void* d_ws, size_t ws_size,
                              hipStream_t stream) {
  const float* x      = (const float*)d_in[0];
  const float* w_exp  = (const float*)d_in[1];
  const float* b_exp  = (const float*)d_in[2];
  const float* w_dw   = (const float*)d_in[3];
  const float* b_dw   = (const float*)d_in[4];
  const float* w_se1  = (const float*)d_in[5];
  const float* b_se1  = (const float*)d_in[6];
  const float* w_se2  = (const float*)d_in[7];
  const float* b_se2  = (const float*)d_in[8];
  const float* w_proj = (const float*)d_in[9];
  const float* b_proj = (const float*)d_in[10];
  float* out = (float*)d_out;

  char* ws = (char*)d_ws;
  const size_t SZ_W  = (size_t)CE * CI * 2;            // 110592 B
  const size_t SZ_ED = (size_t)NB * CE * HW * 2;       // 57802752 B
  const size_t SZ_S  = (size_t)NB * CE * 4;            // 147456 B
  _Float16* w_exp_h  = (_Float16*)(ws);
  _Float16* w_proj_h = (_Float16*)(ws + SZ_W);
  _Float16* e_s      = (_Float16*)(ws + 2 * SZ_W);
  _Float16* d_t      = (_Float16*)(ws + 2 * SZ_W + SZ_ED);     // [n][72][784][8]
  float*    d_sums   = (float*)   (ws + 2 * SZ_W + 2 * SZ_ED);
  float*    g1       = (float*)   (ws + 2 * SZ_W + 2 * SZ_ED + SZ_S);
  _Float16* g2h      = (_Float16*)(ws + 2 * SZ_W + 2 * SZ_ED + 2 * SZ_S);
  // total ws use: ~116.2 MB

  k0_cvt_w<<<(CE * CI + 255) / 256, 256, 0, stream>>>(w_exp, w_proj, w_exp_h, w_proj_h);
  k1_expand<<<dim3(7, 6, NB), 384, 0, stream>>>(x, w_exp_h, b_exp, e_s);
  k2_dw<<<dim3(72, NB), 256, 0, stream>>>(e_s, w_dw, b_dw, d_t, d_sums);
  k3a_fc1<<<dim3(36, NB), 256, 0, stream>>>(d_sums, w_se1, b_se1, g1);
  k3b_fc2<<<dim3(144, NB), 256, 0, stream>>>(g1, w_se2, b_se2, g2h);
  k4_proj<<<dim3(7, NB), 384, 0, stream>>>(d_t, g2h, w_proj_h, b_proj, x, out);
}

// Round 6
// 191.692 us; speedup vs baseline: 1.1981x; 1.0313x over previous
//
#include <hip/hip_runtime.h>

typedef _Float16 v8h __attribute__((ext_vector_type(8)));
typedef _Float16 v4h __attribute__((ext_vector_type(4)));
typedef _Float16 v4h_a4 __attribute__((ext_vector_type(4), aligned(4)));
typedef _Float16 v2h __attribute__((ext_vector_type(2)));
typedef float v4f __attribute__((ext_vector_type(4)));

#define NB 64
#define CI 96
#define CE 576
#define CO 96
#define HW 784
#define SEC 144

#if defined(__has_builtin)
#if __has_builtin(__builtin_amdgcn_fdot2)
#define HAVE_FDOT2 1
#endif
#endif

__device__ __forceinline__ float fdot2(v2h a, v2h b, float c) {
#ifdef HAVE_FDOT2
  return __builtin_amdgcn_fdot2(a, b, c, false);
#else
  return (float)a[0] * (float)b[0] + ((float)a[1] * (float)b[1] + c);
#endif
}

// ---------------- K0: convert GEMM weights to fp16 (integers +-127, exact) ----
__global__ __launch_bounds__(256) void k0_cvt_w(const float* __restrict__ w_exp,
                                                const float* __restrict__ w_proj,
                                                _Float16* __restrict__ w_exp_h,
                                                _Float16* __restrict__ w_proj_h) {
  int i = blockIdx.x * 256 + threadIdx.x;
  if (i < CE * CI) {                 // 55296 == CE*CI == CO*CE
    w_exp_h[i]  = (_Float16)w_exp[i];
    w_proj_h[i] = (_Float16)w_proj[i];
  }
}

// ---------------- K1: expand 1x1 + hardswish + requant -> e_s fp16 [n][c][hw] --
// LDS holds x-tile in MFMA-B-fragment packed layout: X[s][t][lane][8j], tile
// padded 512->520 halves so t-stride (260 dw) == 4 mod 32 -> staging writes ~2-way.
// Fragment reads are consecutive-16B ds_read_b128 (conflict-free).
__global__ __launch_bounds__(384) void k1_expand(const float* __restrict__ x,
                                                 const _Float16* __restrict__ w_exp_h,
                                                 const float* __restrict__ b_exp,
                                                 _Float16* __restrict__ e_s) {
  __shared__ _Float16 xf[3 * 7 * 520];   // 21840 B
  const int tid = threadIdx.x;
  const int n   = blockIdx.z;
  const int co0 = blockIdx.y * 96;
  const int hw0 = blockIdx.x * 112;

#pragma unroll
  for (int it = 0; it < 7; ++it) {       // 7*384 == CI*28
    int idx = it * 384 + tid;
    int c = idx / 28, seg = idx % 28;
    const float4 v = *(const float4*)&x[(n * CI + c) * HW + hw0 + seg * 4];
    int s = c >> 5, q = (c >> 3) & 3, j = c & 7;
    int t = seg >> 2, l0 = (seg & 3) * 4;
    int base = (s * 7 + t) * 520 + (q * 16 + l0) * 8 + j;
    xf[base]      = (_Float16)(v.x - 128.0f);
    xf[base + 8]  = (_Float16)(v.y - 128.0f);
    xf[base + 16] = (_Float16)(v.z - 128.0f);
    xf[base + 24] = (_Float16)(v.w - 128.0f);
  }
  __syncthreads();

  const int wv = tid >> 6, lane = tid & 63;
  const int l15 = lane & 15, q = lane >> 4;

  const _Float16* wrow = &w_exp_h[(co0 + wv * 16 + l15) * CI + q * 8];
  v8h a0 = *(const v8h*)(wrow);
  v8h a1 = *(const v8h*)(wrow + 32);
  v8h a2 = *(const v8h*)(wrow + 64);

  v4f acc[7];
#pragma unroll
  for (int t = 0; t < 7; ++t) acc[t] = (v4f){0.f, 0.f, 0.f, 0.f};

#pragma unroll
  for (int t = 0; t < 7; ++t) {
    v8h b0 = *(const v8h*)&xf[(0 * 7 + t) * 520 + lane * 8];
    v8h b1 = *(const v8h*)&xf[(1 * 7 + t) * 520 + lane * 8];
    v8h b2 = *(const v8h*)&xf[(2 * 7 + t) * 520 + lane * 8];
    acc[t] = __builtin_amdgcn_mfma_f32_16x16x32_f16(a0, b0, acc[t], 0, 0, 0);
    acc[t] = __builtin_amdgcn_mfma_f32_16x16x32_f16(a1, b1, acc[t], 0, 0, 0);
    acc[t] = __builtin_amdgcn_mfma_f32_16x16x32_f16(a2, b2, acc[t], 0, 0, 0);
  }

  float bia[4];
#pragma unroll
  for (int r = 0; r < 4; ++r) bia[r] = b_exp[co0 + wv * 16 + q * 4 + r];

#pragma unroll
  for (int t = 0; t < 7; ++t) {
#pragma unroll
    for (int r = 0; r < 4; ++r) {
      int co = co0 + wv * 16 + q * 4 + r;
      int hw = hw0 + t * 16 + l15;
      float deq = (acc[t][r] + bia[r]) * 5.0e-4f;            // S_IN * W_SCALE
      float cl  = fminf(fmaxf(deq + 3.0f, 0.0f), 6.0f);
      float hs  = deq * cl * (1.0f / 6.0f);
      float ev  = fminf(fmaxf(hs * 25.0f, -128.0f), 127.0f); // (e - 128)
      e_s[(n * CE + co) * HW + hw] = (_Float16)ev;
    }
  }
}

// ---------------- K2: depthwise 5x5 + hardswish + requant + pool sums ---------
// block: (c-group of 8, n); 256 thr. Image rows at half-offset 6 so window
// loads are aligned ds_read_b64. d_tile in [c][hw] layout: conv writes are
// aligned b64 (lane stride 14 dw, free), readout consecutive-half u16
// (conflict-free) -> coalesced v8h global store of k-packed d_t[n][cg][hw][8].
__global__ __launch_bounds__(256, 5) void k2_dw(const _Float16* __restrict__ e_s,
                                                const float* __restrict__ w_dw,
                                                const float* __restrict__ b_dw,
                                                _Float16* __restrict__ d_t,
                                                float* __restrict__ d_sums) {
  __shared__ _Float16 e_lds[8][32][36];   // row stride 72B = 18 banks (gcd 2 -> free)
  __shared__ _Float16 w_pairs[8][5][8];   // [c][dy][w0,w1,w2,w3, w1,w2,w3,w4]
  __shared__ _Float16 d_tile[8][784];     // [c][hw]
  const int tid = threadIdx.x;
  const int n = blockIdx.y;
  const int c0 = blockIdx.x * 8;

  // zero the whole input buffer (covers halo)
  {
    unsigned long long* z = (unsigned long long*)&e_lds[0][0][0];
    for (int idx = tid; idx < 8 * 32 * 36 * 2 / 8; idx += 256) z[idx] = 0ull;
  }
  // stage duplicated weight pairs (f16, exact for int weights)
  for (int idx = tid; idx < 320; idx += 256) {
    int c = idx / 40, r = idx % 40, dy = r / 8, k = r % 8;
    int tap = (k < 4) ? k : (k - 3);
    w_pairs[c][dy][k] = (_Float16)w_dw[(c0 + c) * 25 + dy * 5 + tap];
  }
  __syncthreads();
  // stage interior rows: 8 ch * 28 rows * 7 chunks; pixel p -> half p+6
  for (int idx = tid; idx < 1568; idx += 256) {
    int c = idx / 196, r = idx % 196, y = r / 7, j = r % 7;
    v4h v = *(const v4h*)&e_s[(n * CE + c0 + c) * HW + y * 28 + j * 4];
    *(v4h_a4*)&e_lds[c][2 + y][6 + j * 4] = v;   // half-offset 6: 4B aligned
  }
  __syncthreads();

  const int c = tid >> 5, l = tid & 31;
  // hoist weights into registers
  v2h W01[5], W23[5], W12[5], W34[5];
  float W0s[5], W4s[5];
#pragma unroll
  for (int dy = 0; dy < 5; ++dy) {
    W01[dy] = *(const v2h*)&w_pairs[c][dy][0];
    W23[dy] = *(const v2h*)&w_pairs[c][dy][2];
    W12[dy] = *(const v2h*)&w_pairs[c][dy][4];
    W34[dy] = *(const v2h*)&w_pairs[c][dy][6];
    W0s[dy] = (float)W01[dy][0];
    W4s[dy] = (float)W34[dy][1];
  }
  const float bc = b_dw[c0 + c];

  float csum = 0.0f;
  if (l < 28) {
    const int y = l;   // output row; input rows y-2..y+2 -> LDS rows y..y+4
    // window pairs: P0=(x0-2,x0-1) P1=(x0,x0+1) P2=(x0+2,x0+3) P3=(x0+4,x0+5)
    // pixel p lives at half p+6 -> both v4h loads 8B-aligned
    v2h P0[5], P1[5], P2[5], P3[5];
#pragma unroll
    for (int dy = 0; dy < 5; ++dy) {
      const _Float16* row = &e_lds[c][y + dy][0];
      v4h w01 = *(const v4h*)(row + 4);   // halves 4..7
      v4h w23 = *(const v4h*)(row + 8);   // halves 8..11
      P0[dy] = (v2h){w01[0], w01[1]};
      P1[dy] = (v2h){w01[2], w01[3]};
      P2[dy] = (v2h){w23[0], w23[1]};
      P3[dy] = (v2h){w23[2], w23[3]};
    }
#pragma unroll
    for (int x0 = 0; x0 < 28; x0 += 4) {
      float o0 = bc, o1 = bc, o2 = bc, o3 = bc;
#pragma unroll
      for (int dy = 0; dy < 5; ++dy) {
        o0 = fdot2(P0[dy], W01[dy], o0);
        o0 = fdot2(P1[dy], W23[dy], o0);
        o0 += (float)P2[dy][0] * W4s[dy];
        o1 += (float)P0[dy][1] * W0s[dy];
        o1 = fdot2(P1[dy], W12[dy], o1);
        o1 = fdot2(P2[dy], W34[dy], o1);
        o2 = fdot2(P1[dy], W01[dy], o2);
        o2 = fdot2(P2[dy], W23[dy], o2);
        o2 += (float)P3[dy][0] * W4s[dy];
        o3 += (float)P1[dy][1] * W0s[dy];
        o3 = fdot2(P2[dy], W12[dy], o3);
        o3 = fdot2(P3[dy], W34[dy], o3);
      }
      v4h dv;
      float oo[4] = {o0, o1, o2, o3};
#pragma unroll
      for (int i = 0; i < 4; ++i) {
        float deq = oo[i] * 4.0e-4f;            // S1 * W_SCALE
        float cl  = fminf(fmaxf(deq + 3.0f, 0.0f), 6.0f);
        float dvv = fminf(fmaxf(deq * cl * (25.0f / 6.0f), -128.0f), 127.0f); // d-128
        dv[i] = (_Float16)dvv;
        csum += dvv;
      }
      *(v4h*)&d_tile[c][y * 28 + x0] = dv;       // aligned b64, lane stride 14 dw
      if (x0 < 24) {
#pragma unroll
        for (int dy = 0; dy < 5; ++dy) {
          const _Float16* row = &e_lds[c][y + dy][0];
          v4h nw = *(const v4h*)(row + x0 + 12);  // pixels x0+6..x0+9, aligned
          P0[dy] = P2[dy];
          P1[dy] = P3[dy];
          P2[dy] = (v2h){nw[0], nw[1]};
          P3[dy] = (v2h){nw[2], nw[3]};
        }
      }
    }
  }
#pragma unroll
  for (int m = 16; m >= 1; m >>= 1) csum += __shfl_xor(csum, m);
  if (l == 0) d_sums[n * CE + c0 + c] = csum;

  __syncthreads();
  // coalesced writeout: thread -> hw, consecutive-half LDS reads (conflict-free)
  const size_t obase = ((size_t)n * 72 + (c0 >> 3)) * 784;
  for (int hw = tid; hw < 784; hw += 256) {
    v8h o;
#pragma unroll
    for (int j = 0; j < 8; ++j) o[j] = d_tile[j][hw];
    *(v8h*)&d_t[(obase + hw) * 8] = o;
  }
}

// ---------------- K3a: SE fc1 — one wave per (n, o) dot of length 576 ---------
__global__ __launch_bounds__(256) void k3a_fc1(const float* __restrict__ d_sums,
                                               const float* __restrict__ w_se1,
                                               const float* __restrict__ b_se1,
                                               float* __restrict__ g1) {
  const int tid = threadIdx.x;
  const int wv = tid >> 6, lane = tid & 63;
  const int n = blockIdx.y;
  const int o = blockIdx.x * 4 + wv;       // 144 outputs
  const float* wrow = &w_se1[o * CE];
  const float* srow = &d_sums[n * CE];
  float p = 0.f;
#pragma unroll
  for (int s = 0; s < 9; ++s) {
    int cc = lane + s * 64;
    p += wrow[cc] * srow[cc];
  }
#pragma unroll
  for (int m = 32; m >= 1; m >>= 1) p += __shfl_xor(p, m);
  if (lane == 0) {
    // pooled-z = d_sums/784 (d_t already stores d-128)
    float deq = (p * (1.0f / 784.0f) + b_se1[o]) * 4.0e-4f;  // S2 * W_SCALE
    g1[n * SEC + o] = fminf(fmaxf(deq * 33.3333333f + 128.0f, 0.0f), 255.0f) - 128.0f;
  }
}

// ---------------- K3b: SE fc2 + hardsigmoid -> f16 gate table -----------------
__global__ __launch_bounds__(256) void k3b_fc2(const float* __restrict__ g1,
                                               const float* __restrict__ w_se2,
                                               const float* __restrict__ b_se2,
                                               _Float16* __restrict__ g2h) {
  const int tid = threadIdx.x;
  const int wv = tid >> 6, lane = tid & 63;
  const int n = blockIdx.y;
  const int o = blockIdx.x * 4 + wv;       // 576 outputs
  const float* wrow = &w_se2[o * SEC];
  const float* grow = &g1[n * SEC];
  float p = wrow[lane] * grow[lane] + wrow[lane + 64] * grow[lane + 64];
  if (lane < 16) p += wrow[lane + 128] * grow[lane + 128];
#pragma unroll
  for (int m = 32; m >= 1; m >>= 1) p += __shfl_xor(p, m);
  if (lane == 0) {
    float deq = (p + b_se2[o]) * 3.0e-4f;  // S_SE1 * W_SCALE
    g2h[n * CE + o] =
        (_Float16)(fminf(fmaxf(deq + 3.0f, 0.0f), 6.0f) * (1.0f / 6.0f)); // hardsigmoid
  }
}

// ---------------- K4: gated project 1x1 + residual add -> out fp32 -----------
// No LDS/barriers, 7 independent accumulators per wave for load ILP.
// Gate folded into the A fragment (A and B share k-fragment indexing).
// M-split co-groups of 48 (3 waves/block) -> 896 blocks for CU balance;
// d_t re-read x2 is absorbed by L3 (57.8 MB fits in 256 MB).
__global__ __launch_bounds__(192) void k4_proj(const _Float16* __restrict__ d_t,
                                               const _Float16* __restrict__ g2h,
                                               const _Float16* __restrict__ w_proj_h,
                                               const float* __restrict__ b_proj,
                                               const float* __restrict__ x,
                                               float* __restrict__ out) {
  const int tid = threadIdx.x;
  const int n = blockIdx.z;
  const int co0 = blockIdx.y * 48;
  const int hw0 = blockIdx.x * 112;
  const int wv = tid >> 6, lane = tid & 63;
  const int l15 = lane & 15, q = lane >> 4;

  v4f acc[7];
#pragma unroll
  for (int t = 0; t < 7; ++t) acc[t] = (v4f){0.f, 0.f, 0.f, 0.f};

  const _Float16* dbase = d_t + (((size_t)n * 72 + q) * 784 + hw0 + l15) * 8;
  const _Float16* abase = &w_proj_h[(co0 + wv * 16 + l15) * CE + q * 8];
  const _Float16* gbase = &g2h[(size_t)n * CE + q * 8];

  for (int ks = 0; ks < 18; ++ks) {
    v8h a = *(const v8h*)(abase + ks * 32);
    v8h g = *(const v8h*)(gbase + ks * 32);
    v8h ag = a * g;   // 4x v_pk_mul_f16, shared across the 7 MFMAs
    const _Float16* dk = dbase + (size_t)ks * (4 * 784 * 8);
#pragma unroll
    for (int t = 0; t < 7; ++t) {
      v8h b = *(const v8h*)(dk + t * (16 * 8));
      acc[t] = __builtin_amdgcn_mfma_f32_16x16x32_f16(ag, b, acc[t], 0, 0, 0);
    }
  }

  float bia[4];
#pragma unroll
  for (int r = 0; r < 4; ++r) bia[r] = b_proj[co0 + wv * 16 + q * 4 + r];

#pragma unroll
  for (int t = 0; t < 7; ++t) {
#pragma unroll
    for (int r = 0; r < 4; ++r) {
      int co = co0 + wv * 16 + q * 4 + r;
      int hw = hw0 + t * 16 + l15;
      float p = fminf(fmaxf((acc[t][r] + bia[r]) * 4.0e-4f * 20.0f + 128.0f, 0.0f), 255.0f);
      float xv = x[(n * CO + co) * HW + hw];
      float o = (xv - 128.0f) * 0.8333333333f + (p - 128.0f) * 0.8333333333f + 128.0f;
      out[(n * CO + co) * HW + hw] = fminf(fmaxf(o, 0.0f), 255.0f);
    }
  }
}

extern "C" void kernel_launch(void* const* d_in, const int* in_sizes, int n_in,
                              void* d_out, int out_size, void* d_ws, size_t ws_size,
                              hipStream_t stream) {
  const float* x      = (const float*)d_in[0];
  const float* w_exp  = (const float*)d_in[1];
  const float* b_exp  = (const float*)d_in[2];
  const float* w_dw   = (const float*)d_in[3];
  const float* b_dw   = (const float*)d_in[4];
  const float* w_se1  = (const float*)d_in[5];
  const float* b_se1  = (const float*)d_in[6];
  const float* w_se2  = (const float*)d_in[7];
  const float* b_se2  = (const float*)d_in[8];
  const float* w_proj = (const float*)d_in[9];
  const float* b_proj = (const float*)d_in[10];
  float* out = (float*)d_out;

  char* ws = (char*)d_ws;
  const size_t SZ_W  = (size_t)CE * CI * 2;            // 110592 B
  const size_t SZ_ED = (size_t)NB * CE * HW * 2;       // 57802752 B
  const size_t SZ_S  = (size_t)NB * CE * 4;            // 147456 B
  _Float16* w_exp_h  = (_Float16*)(ws);
  _Float16* w_proj_h = (_Float16*)(ws + SZ_W);
  _Float16* e_s      = (_Float16*)(ws + 2 * SZ_W);
  _Float16* d_t      = (_Float16*)(ws + 2 * SZ_W + SZ_ED);     // [n][72][784][8]
  float*    d_sums   = (float*)   (ws + 2 * SZ_W + 2 * SZ_ED);
  float*    g1       = (float*)   (ws + 2 * SZ_W + 2 * SZ_ED + SZ_S);
  _Float16* g2h      = (_Float16*)(ws + 2 * SZ_W + 2 * SZ_ED + 2 * SZ_S);
  // total ws use: ~116.2 MB

  k0_cvt_w<<<(CE * CI + 255) / 256, 256, 0, stream>>>(w_exp, w_proj, w_exp_h, w_proj_h);
  k1_expand<<<dim3(7, 6, NB), 384, 0, stream>>>(x, w_exp_h, b_exp, e_s);
  k2_dw<<<dim3(72, NB), 256, 0, stream>>>(e_s, w_dw, b_dw, d_t, d_sums);
  k3a_fc1<<<dim3(36, NB), 256, 0, stream>>>(d_sums, w_se1, b_se1, g1);
  k3b_fc2<<<dim3(144, NB), 256, 0, stream>>>(g1, w_se2, b_se2, g2h);
  k4_proj<<<dim3(7, 2, NB), 192, 0, stream>>>(d_t, g2h, w_proj_h, b_proj, x, out);
}

// Round 7
// 179.509 us; speedup vs baseline: 1.2794x; 1.0679x over previous
//
#include <hip/hip_runtime.h>

typedef _Float16 v8h __attribute__((ext_vector_type(8)));
typedef _Float16 v4h __attribute__((ext_vector_type(4)));
typedef _Float16 v4h_a4 __attribute__((ext_vector_type(4), aligned(4)));
typedef _Float16 v2h __attribute__((ext_vector_type(2)));
typedef float v4f __attribute__((ext_vector_type(4)));

#define NB 64
#define CI 96
#define CE 576
#define CO 96
#define HW 784
#define SEC 144

#if defined(__has_builtin)
#if __has_builtin(__builtin_amdgcn_fdot2)
#define HAVE_FDOT2 1
#endif
#endif

__device__ __forceinline__ float fdot2(v2h a, v2h b, float c) {
#ifdef HAVE_FDOT2
  return __builtin_amdgcn_fdot2(a, b, c, false);
#else
  return (float)a[0] * (float)b[0] + ((float)a[1] * (float)b[1] + c);
#endif
}

// ---------------- K0: convert GEMM weights to fp16 (integers +-127, exact) ----
__global__ __launch_bounds__(256) void k0_cvt_w(const float* __restrict__ w_exp,
                                                const float* __restrict__ w_proj,
                                                _Float16* __restrict__ w_exp_h,
                                                _Float16* __restrict__ w_proj_h) {
  int i = blockIdx.x * 256 + threadIdx.x;
  if (i < CE * CI) {                 // 55296 == CE*CI == CO*CE
    w_exp_h[i]  = (_Float16)w_exp[i];
    w_proj_h[i] = (_Float16)w_proj[i];
  }
}

// ---------------- K0x: pack x into global MFMA-B-fragment layout --------------
// x_f[n][t][s][lane][8]: t = hw>>4 (49 tiles), s = ci 32-group (3), lane =
// (hw&15) + 16*(ci>>3 & 3), last 8 = consecutive ci. Values are (x-128) f16.
// Fused kernel then loads B-frags as single coalesced b128 per lane.
__global__ __launch_bounds__(256) void k0x_pack(const float* __restrict__ x,
                                                _Float16* __restrict__ x_f) {
  __shared__ _Float16 xl[112][104];   // [hw_local][ci], pad 96->104
  const int tid = threadIdx.x;
  const int n = blockIdx.y;
  const int hw0 = blockIdx.x * 112;

  for (int idx = tid; idx < CI * 28; idx += 256) {
    int c = idx / 28, seg = idx % 28;
    const float4 v = *(const float4*)&x[(n * CI + c) * HW + hw0 + seg * 4];
    int row = seg * 4;
    xl[row + 0][c] = (_Float16)(v.x - 128.0f);
    xl[row + 1][c] = (_Float16)(v.y - 128.0f);
    xl[row + 2][c] = (_Float16)(v.z - 128.0f);
    xl[row + 3][c] = (_Float16)(v.w - 128.0f);
  }
  __syncthreads();

  // 7 t_local * 3 s * 64 lanes = 1344 v8h frags, writes fully coalesced
  for (int idx = tid; idx < 1344; idx += 256) {
    int t_l = idx / 192, rem = idx % 192, s = rem / 64, ln = rem % 64;
    int hw_l = t_l * 16 + (ln & 15), ci = s * 32 + (ln >> 4) * 8;
    v8h o;
#pragma unroll
    for (int j = 0; j < 8; ++j) o[j] = xl[hw_l][ci + j];
    size_t t = (size_t)(blockIdx.x * 7 + t_l);
    *(v8h*)&x_f[(((size_t)n * 49 + t) * 3 + s) * 512 + ln * 8] = o;
  }
}

// ---------------- K12: FUSED expand 1x1 (MFMA) + depthwise 5x5 ---------------
// block = (c-group of 16, n), 512 thr (8 waves). Phase 1: expand GEMM M=16,
// K=96, N=784 from x_f B-frags, hardswish+requant epilogue scatters (e-128)
// f16 straight into the zero-padded conv image in LDS (C-layout: col->hw,
// row->channel). Phase 2: k2's dot2 conv + pool sums. Phase 3: k-packed d_t
// writeout. The 57.8 MB e tensor never touches HBM.
__global__ __launch_bounds__(512, 4) void k12_fused(const _Float16* __restrict__ x_f,
                                                    const _Float16* __restrict__ w_exp_h,
                                                    const float* __restrict__ b_exp,
                                                    const float* __restrict__ w_dw,
                                                    const float* __restrict__ b_dw,
                                                    _Float16* __restrict__ d_t,
                                                    float* __restrict__ d_sums) {
  __shared__ _Float16 e_lds[16][32][36];   // 36864 B, row stride 72B (free 2-way)
  __shared__ _Float16 d_tile[16][784];     // 25088 B
  __shared__ _Float16 w_pairs[16][5][8];   // 1280 B
  const int tid = threadIdx.x;
  const int n = blockIdx.y;
  const int c0 = blockIdx.x * 16;

  // zero the conv image (covers halo)
  {
    unsigned long long* z = (unsigned long long*)&e_lds[0][0][0];
    for (int idx = tid; idx < 16 * 32 * 36 * 2 / 8; idx += 512) z[idx] = 0ull;
  }
  // dw weight pairs [c][dy][w0,w1,w2,w3, w1,w2,w3,w4]
  for (int idx = tid; idx < 640; idx += 512) {
    int c = idx / 40, r = idx % 40, dy = r / 8, k = r % 8;
    int tap = (k < 4) ? k : (k - 3);
    w_pairs[c][dy][k] = (_Float16)w_dw[(c0 + c) * 25 + dy * 5 + tap];
  }
  __syncthreads();

  const int wv = tid >> 6, lane = tid & 63;
  const int l15 = lane & 15, q = lane >> 4;

  // ---- phase 1: expand GEMM ----
  {
    const _Float16* wrow = &w_exp_h[(c0 + l15) * CI + q * 8];
    v8h a0 = *(const v8h*)(wrow);
    v8h a1 = *(const v8h*)(wrow + 32);
    v8h a2 = *(const v8h*)(wrow + 64);
    float bia[4];
#pragma unroll
    for (int r = 0; r < 4; ++r) bia[r] = b_exp[c0 + q * 4 + r];

    const _Float16* xb = x_f + (size_t)n * (49 * 3 * 512) + lane * 8;
    for (int t = wv; t < 49; t += 8) {
      const _Float16* xt = xb + (size_t)t * (3 * 512);
      v8h b0 = *(const v8h*)(xt);
      v8h b1 = *(const v8h*)(xt + 512);
      v8h b2 = *(const v8h*)(xt + 1024);
      v4f acc = (v4f){0.f, 0.f, 0.f, 0.f};
      acc = __builtin_amdgcn_mfma_f32_16x16x32_f16(a0, b0, acc, 0, 0, 0);
      acc = __builtin_amdgcn_mfma_f32_16x16x32_f16(a1, b1, acc, 0, 0, 0);
      acc = __builtin_amdgcn_mfma_f32_16x16x32_f16(a2, b2, acc, 0, 0, 0);
      int hw = t * 16 + l15;
      int y = hw / 28, xx = hw - y * 28;
#pragma unroll
      for (int r = 0; r < 4; ++r) {
        float deq = (acc[r] + bia[r]) * 5.0e-4f;            // S_IN * W_SCALE
        float cl  = fminf(fmaxf(deq + 3.0f, 0.0f), 6.0f);
        float ev  = fminf(fmaxf(deq * cl * (25.0f / 6.0f), -128.0f), 127.0f); // e-128
        e_lds[q * 4 + r][2 + y][6 + xx] = (_Float16)ev;
      }
    }
  }
  __syncthreads();

  // ---- phase 2: depthwise 5x5 (k2's dot2 form) ----
  const int c = tid >> 5, l = tid & 31;
  v2h W01[5], W23[5], W12[5], W34[5];
  float W0s[5], W4s[5];
#pragma unroll
  for (int dy = 0; dy < 5; ++dy) {
    W01[dy] = *(const v2h*)&w_pairs[c][dy][0];
    W23[dy] = *(const v2h*)&w_pairs[c][dy][2];
    W12[dy] = *(const v2h*)&w_pairs[c][dy][4];
    W34[dy] = *(const v2h*)&w_pairs[c][dy][6];
    W0s[dy] = (float)W01[dy][0];
    W4s[dy] = (float)W34[dy][1];
  }
  const float bc = b_dw[c0 + c];

  float csum = 0.0f;
  if (l < 28) {
    const int y = l;
    v2h P0[5], P1[5], P2[5], P3[5];
#pragma unroll
    for (int dy = 0; dy < 5; ++dy) {
      const _Float16* row = &e_lds[c][y + dy][0];
      v4h w01 = *(const v4h*)(row + 4);
      v4h w23 = *(const v4h*)(row + 8);
      P0[dy] = (v2h){w01[0], w01[1]};
      P1[dy] = (v2h){w01[2], w01[3]};
      P2[dy] = (v2h){w23[0], w23[1]};
      P3[dy] = (v2h){w23[2], w23[3]};
    }
#pragma unroll
    for (int x0 = 0; x0 < 28; x0 += 4) {
      float o0 = bc, o1 = bc, o2 = bc, o3 = bc;
#pragma unroll
      for (int dy = 0; dy < 5; ++dy) {
        o0 = fdot2(P0[dy], W01[dy], o0);
        o0 = fdot2(P1[dy], W23[dy], o0);
        o0 += (float)P2[dy][0] * W4s[dy];
        o1 += (float)P0[dy][1] * W0s[dy];
        o1 = fdot2(P1[dy], W12[dy], o1);
        o1 = fdot2(P2[dy], W34[dy], o1);
        o2 = fdot2(P1[dy], W01[dy], o2);
        o2 = fdot2(P2[dy], W23[dy], o2);
        o2 += (float)P3[dy][0] * W4s[dy];
        o3 += (float)P1[dy][1] * W0s[dy];
        o3 = fdot2(P2[dy], W12[dy], o3);
        o3 = fdot2(P3[dy], W34[dy], o3);
      }
      v4h dv;
      float oo[4] = {o0, o1, o2, o3};
#pragma unroll
      for (int i = 0; i < 4; ++i) {
        float deq = oo[i] * 4.0e-4f;            // S1 * W_SCALE
        float cl  = fminf(fmaxf(deq + 3.0f, 0.0f), 6.0f);
        float dvv = fminf(fmaxf(deq * cl * (25.0f / 6.0f), -128.0f), 127.0f); // d-128
        dv[i] = (_Float16)dvv;
        csum += dvv;
      }
      *(v4h*)&d_tile[c][y * 28 + x0] = dv;
      if (x0 < 24) {
#pragma unroll
        for (int dy = 0; dy < 5; ++dy) {
          const _Float16* row = &e_lds[c][y + dy][0];
          v4h nw = *(const v4h*)(row + x0 + 12);
          P0[dy] = P2[dy];
          P1[dy] = P3[dy];
          P2[dy] = (v2h){nw[0], nw[1]};
          P3[dy] = (v2h){nw[2], nw[3]};
        }
      }
    }
  }
#pragma unroll
  for (int m = 16; m >= 1; m >>= 1) csum += __shfl_xor(csum, m);
  if (l == 0) d_sums[n * CE + c0 + c] = csum;

  __syncthreads();
  // ---- phase 3: k-packed writeout d_t[n][cg][hw][8], 2 cgroups ----
  const size_t obase = ((size_t)n * 72 + (c0 >> 3)) * 784;
  for (int hw = tid; hw < 784; hw += 512) {
    v8h o0, o1;
#pragma unroll
    for (int j = 0; j < 8; ++j) { o0[j] = d_tile[j][hw]; o1[j] = d_tile[8 + j][hw]; }
    *(v8h*)&d_t[(obase + hw) * 8] = o0;
    *(v8h*)&d_t[(obase + 784 + hw) * 8] = o1;
  }
}

// ---------------- K3a: SE fc1 — one wave per (n, o) dot of length 576 ---------
__global__ __launch_bounds__(256) void k3a_fc1(const float* __restrict__ d_sums,
                                               const float* __restrict__ w_se1,
                                               const float* __restrict__ b_se1,
                                               float* __restrict__ g1) {
  const int tid = threadIdx.x;
  const int wv = tid >> 6, lane = tid & 63;
  const int n = blockIdx.y;
  const int o = blockIdx.x * 4 + wv;       // 144 outputs
  const float* wrow = &w_se1[o * CE];
  const float* srow = &d_sums[n * CE];
  float p = 0.f;
#pragma unroll
  for (int s = 0; s < 9; ++s) {
    int cc = lane + s * 64;
    p += wrow[cc] * srow[cc];
  }
#pragma unroll
  for (int m = 32; m >= 1; m >>= 1) p += __shfl_xor(p, m);
  if (lane == 0) {
    float deq = (p * (1.0f / 784.0f) + b_se1[o]) * 4.0e-4f;  // S2 * W_SCALE
    g1[n * SEC + o] = fminf(fmaxf(deq * 33.3333333f + 128.0f, 0.0f), 255.0f) - 128.0f;
  }
}

// ---------------- K3b: SE fc2 + hardsigmoid -> f16 gate table -----------------
__global__ __launch_bounds__(256) void k3b_fc2(const float* __restrict__ g1,
                                               const float* __restrict__ w_se2,
                                               const float* __restrict__ b_se2,
                                               _Float16* __restrict__ g2h) {
  const int tid = threadIdx.x;
  const int wv = tid >> 6, lane = tid & 63;
  const int n = blockIdx.y;
  const int o = blockIdx.x * 4 + wv;       // 576 outputs
  const float* wrow = &w_se2[o * SEC];
  const float* grow = &g1[n * SEC];
  float p = wrow[lane] * grow[lane] + wrow[lane + 64] * grow[lane + 64];
  if (lane < 16) p += wrow[lane + 128] * grow[lane + 128];
#pragma unroll
  for (int m = 32; m >= 1; m >>= 1) p += __shfl_xor(p, m);
  if (lane == 0) {
    float deq = (p + b_se2[o]) * 3.0e-4f;  // S_SE1 * W_SCALE
    g2h[n * CE + o] =
        (_Float16)(fminf(fmaxf(deq + 3.0f, 0.0f), 6.0f) * (1.0f / 6.0f)); // hardsigmoid
  }
}

// ---------------- K4: gated project 1x1 + residual add -> out fp32 -----------
// No LDS/barriers, 7 independent accumulators per wave for load ILP.
// Gate folded into the A fragment. M-split co-groups of 48 -> 896 blocks.
__global__ __launch_bounds__(192) void k4_proj(const _Float16* __restrict__ d_t,
                                               const _Float16* __restrict__ g2h,
                                               const _Float16* __restrict__ w_proj_h,
                                               const float* __restrict__ b_proj,
                                               const float* __restrict__ x,
                                               float* __restrict__ out) {
  const int tid = threadIdx.x;
  const int n = blockIdx.z;
  const int co0 = blockIdx.y * 48;
  const int hw0 = blockIdx.x * 112;
  const int wv = tid >> 6, lane = tid & 63;
  const int l15 = lane & 15, q = lane >> 4;

  v4f acc[7];
#pragma unroll
  for (int t = 0; t < 7; ++t) acc[t] = (v4f){0.f, 0.f, 0.f, 0.f};

  const _Float16* dbase = d_t + (((size_t)n * 72 + q) * 784 + hw0 + l15) * 8;
  const _Float16* abase = &w_proj_h[(co0 + wv * 16 + l15) * CE + q * 8];
  const _Float16* gbase = &g2h[(size_t)n * CE + q * 8];

  for (int ks = 0; ks < 18; ++ks) {
    v8h a = *(const v8h*)(abase + ks * 32);
    v8h g = *(const v8h*)(gbase + ks * 32);
    v8h ag = a * g;   // 4x v_pk_mul_f16, shared across the 7 MFMAs
    const _Float16* dk = dbase + (size_t)ks * (4 * 784 * 8);
#pragma unroll
    for (int t = 0; t < 7; ++t) {
      v8h b = *(const v8h*)(dk + t * (16 * 8));
      acc[t] = __builtin_amdgcn_mfma_f32_16x16x32_f16(ag, b, acc[t], 0, 0, 0);
    }
  }

  float bia[4];
#pragma unroll
  for (int r = 0; r < 4; ++r) bia[r] = b_proj[co0 + wv * 16 + q * 4 + r];

#pragma unroll
  for (int t = 0; t < 7; ++t) {
#pragma unroll
    for (int r = 0; r < 4; ++r) {
      int co = co0 + wv * 16 + q * 4 + r;
      int hw = hw0 + t * 16 + l15;
      float p = fminf(fmaxf((acc[t][r] + bia[r]) * 4.0e-4f * 20.0f + 128.0f, 0.0f), 255.0f);
      float xv = x[(n * CO + co) * HW + hw];
      float o = (xv - 128.0f) * 0.8333333333f + (p - 128.0f) * 0.8333333333f + 128.0f;
      out[(n * CO + co) * HW + hw] = fminf(fmaxf(o, 0.0f), 255.0f);
    }
  }
}

extern "C" void kernel_launch(void* const* d_in, const int* in_sizes, int n_in,
                              void* d_out, int out_size, void* d_ws, size_t ws_size,
                              hipStream_t stream) {
  const float* x      = (const float*)d_in[0];
  const float* w_exp  = (const float*)d_in[1];
  const float* b_exp  = (const float*)d_in[2];
  const float* w_dw   = (const float*)d_in[3];
  const float* b_dw   = (const float*)d_in[4];
  const float* w_se1  = (const float*)d_in[5];
  const float* b_se1  = (const float*)d_in[6];
  const float* w_se2  = (const float*)d_in[7];
  const float* b_se2  = (const float*)d_in[8];
  const float* w_proj = (const float*)d_in[9];
  const float* b_proj = (const float*)d_in[10];
  float* out = (float*)d_out;

  char* ws = (char*)d_ws;
  const size_t SZ_W  = (size_t)CE * CI * 2;            // 110592 B
  const size_t SZ_XF = (size_t)NB * 49 * 3 * 512 * 2;  // 9633792 B
  const size_t SZ_D  = (size_t)NB * CE * HW * 2;       // 57802752 B
  const size_t SZ_S  = (size_t)NB * CE * 4;            // 147456 B
  _Float16* w_exp_h  = (_Float16*)(ws);
  _Float16* w_proj_h = (_Float16*)(ws + SZ_W);
  _Float16* x_f      = (_Float16*)(ws + 2 * SZ_W);
  _Float16* d_t      = (_Float16*)(ws + 2 * SZ_W + SZ_XF);    // [n][72][784][8]
  float*    d_sums   = (float*)   (ws + 2 * SZ_W + SZ_XF + SZ_D);
  float*    g1       = (float*)   (ws + 2 * SZ_W + SZ_XF + SZ_D + SZ_S);
  _Float16* g2h      = (_Float16*)(ws + 2 * SZ_W + SZ_XF + SZ_D + 2 * SZ_S);
  // total ws use: ~68 MB

  k0_cvt_w<<<(CE * CI + 255) / 256, 256, 0, stream>>>(w_exp, w_proj, w_exp_h, w_proj_h);
  k0x_pack<<<dim3(7, NB), 256, 0, stream>>>(x, x_f);
  k12_fused<<<dim3(36, NB), 512, 0, stream>>>(x_f, w_exp_h, b_exp, w_dw, b_dw, d_t, d_sums);
  k3a_fc1<<<dim3(36, NB), 256, 0, stream>>>(d_sums, w_se1, b_se1, g1);
  k3b_fc2<<<dim3(144, NB), 256, 0, stream>>>(g1, w_se2, b_se2, g2h);
  k4_proj<<<dim3(7, 2, NB), 192, 0, stream>>>(d_t, g2h, w_proj_h, b_proj, x, out);
}

// Round 9
// 175.619 us; speedup vs baseline: 1.3078x; 1.0222x over previous
//
#include <hip/hip_runtime.h>

typedef _Float16 v8h __attribute__((ext_vector_type(8)));
typedef _Float16 v4h __attribute__((ext_vector_type(4)));
typedef _Float16 v2h __attribute__((ext_vector_type(2)));
typedef float v4f __attribute__((ext_vector_type(4)));

#define NB 64
#define CI 96
#define CE 576
#define CO 96
#define HW 784
#define SEC 144

#if defined(__has_builtin)
#if __has_builtin(__builtin_amdgcn_fdot2)
#define HAVE_FDOT2 1
#endif
#endif

__device__ __forceinline__ float fdot2(v2h a, v2h b, float c) {
#ifdef HAVE_FDOT2
  return __builtin_amdgcn_fdot2(a, b, c, false);
#else
  return (float)a[0] * (float)b[0] + ((float)a[1] * (float)b[1] + c);
#endif
}

// ---------------- K0: convert GEMM weights to fp16 (integers +-127, exact) ----
__global__ __launch_bounds__(256) void k0_cvt_w(const float* __restrict__ w_exp,
                                                const float* __restrict__ w_proj,
                                                _Float16* __restrict__ w_exp_h,
                                                _Float16* __restrict__ w_proj_h) {
  int i = blockIdx.x * 256 + threadIdx.x;
  if (i < CE * CI) {                 // 55296 == CE*CI == CO*CE
    w_exp_h[i]  = (_Float16)w_exp[i];
    w_proj_h[i] = (_Float16)w_proj[i];
  }
}

// ---------------- K0x: pack x into global MFMA-B-fragment layout --------------
// x_f[n][t][s][lane][8]: t = hw>>4 (49 tiles), s = ci 32-group (3).
__global__ __launch_bounds__(256) void k0x_pack(const float* __restrict__ x,
                                                _Float16* __restrict__ x_f) {
  __shared__ _Float16 xl[112][104];   // [hw_local][ci], pad 96->104
  const int tid = threadIdx.x;
  const int n = blockIdx.y;
  const int hw0 = blockIdx.x * 112;

  for (int idx = tid; idx < CI * 28; idx += 256) {
    int c = idx / 28, seg = idx % 28;
    const float4 v = *(const float4*)&x[(n * CI + c) * HW + hw0 + seg * 4];
    int row = seg * 4;
    xl[row + 0][c] = (_Float16)(v.x - 128.0f);
    xl[row + 1][c] = (_Float16)(v.y - 128.0f);
    xl[row + 2][c] = (_Float16)(v.z - 128.0f);
    xl[row + 3][c] = (_Float16)(v.w - 128.0f);
  }
  __syncthreads();

  for (int idx = tid; idx < 1344; idx += 256) {
    int t_l = idx / 192, rem = idx % 192, s = rem / 64, ln = rem % 64;
    int hw_l = t_l * 16 + (ln & 15), ci = s * 32 + (ln >> 4) * 8;
    v8h o;
#pragma unroll
    for (int j = 0; j < 8; ++j) o[j] = xl[hw_l][ci + j];
    size_t t = (size_t)(blockIdx.x * 7 + t_l);
    *(v8h*)&x_f[(((size_t)n * 49 + t) * 3 + s) * 512 + ln * 8] = o;
  }
}

// ---------------- K12: FUSED expand 1x1 (MFMA) + depthwise 5x5 ---------------
// block = (c-group of 16, image-half of 14 rows, n), 512 thr (8 waves).
// LDS ~35 KB -> 4 blocks/CU. Halo rows (+-2) recomputed by the expand MFMA.
// ir0 = input row stored at LDS row 0 = 14h-2 for BOTH halves; rows that are
// never written (y<0 top / y>27 bottom) stay zero = the conv halo.
__global__ __launch_bounds__(512, 8) void k12_fused(const _Float16* __restrict__ x_f,
                                                    const _Float16* __restrict__ w_exp_h,
                                                    const float* __restrict__ b_exp,
                                                    const float* __restrict__ w_dw,
                                                    const float* __restrict__ b_dw,
                                                    _Float16* __restrict__ d_t,
                                                    float* __restrict__ d_sums2) {
  __shared__ _Float16 e_lds[16][18][38];   // 21888 B; width 38: all v2h in-row
  __shared__ _Float16 d_tile[16][392];     // 12544 B
  __shared__ _Float16 w_pairs[16][5][8];   // 1280 B
  const int tid = threadIdx.x;
  const int n = blockIdx.z;
  const int h = blockIdx.y;                // image half: rows 14h..14h+13
  const int c0 = blockIdx.x * 16;

  // zero conv image (covers halo + unwritten tail halves)
  {
    unsigned long long* z = (unsigned long long*)&e_lds[0][0][0];
    for (int idx = tid; idx < 16 * 18 * 38 * 2 / 8; idx += 512) z[idx] = 0ull;
  }
  // dw weight pairs [c][dy][w0,w1,w2,w3, w1,w2,w3,w4]
  for (int idx = tid; idx < 640; idx += 512) {
    int c = idx / 40, r = idx % 40, dy = r / 8, k = r % 8;
    int tap = (k < 4) ? k : (k - 3);
    w_pairs[c][dy][k] = (_Float16)w_dw[(c0 + c) * 25 + dy * 5 + tap];
  }
  __syncthreads();

  const int wv = tid >> 6, lane = tid & 63;
  const int l15 = lane & 15, q = lane >> 4;

  // ---- phase 1: expand GEMM over 16 input rows (t-tiles 21h .. 21h+27) ----
  {
    const _Float16* wrow = &w_exp_h[(c0 + l15) * CI + q * 8];
    v8h a0 = *(const v8h*)(wrow);
    v8h a1 = *(const v8h*)(wrow + 32);
    v8h a2 = *(const v8h*)(wrow + 64);
    float bia[4];
#pragma unroll
    for (int r = 0; r < 4; ++r) bia[r] = b_exp[c0 + q * 4 + r];

    const int ir0 = 14 * h - 2;                 // input row at LDS row 0 (FIX)
    const _Float16* xb = x_f + (size_t)n * (49 * 3 * 512) + lane * 8;
    for (int t_l = wv; t_l < 28; t_l += 8) {
      int t = 21 * h + t_l;                     // global 16-hw tile
      const _Float16* xt = xb + (size_t)t * (3 * 512);
      v8h b0 = *(const v8h*)(xt);
      v8h b1 = *(const v8h*)(xt + 512);
      v8h b2 = *(const v8h*)(xt + 1024);
      v4f acc = (v4f){0.f, 0.f, 0.f, 0.f};
      acc = __builtin_amdgcn_mfma_f32_16x16x32_f16(a0, b0, acc, 0, 0, 0);
      acc = __builtin_amdgcn_mfma_f32_16x16x32_f16(a1, b1, acc, 0, 0, 0);
      acc = __builtin_amdgcn_mfma_f32_16x16x32_f16(a2, b2, acc, 0, 0, 0);
      int hw = t * 16 + l15;
      int y = hw / 28, xx = hw - y * 28;
      int r_l = y - ir0;                        // h=0: y+2 in [2,17]; h=1: y-12 in [0,15]
#pragma unroll
      for (int r = 0; r < 4; ++r) {
        float deq = (acc[r] + bia[r]) * 5.0e-4f;            // S_IN * W_SCALE
        float cl  = fminf(fmaxf(deq + 3.0f, 0.0f), 6.0f);
        float ev  = fminf(fmaxf(deq * cl * (25.0f / 6.0f), -128.0f), 127.0f); // e-128
        e_lds[q * 4 + r][r_l][6 + xx] = (_Float16)ev;
      }
    }
  }
  __syncthreads();

  // ---- phase 2: depthwise 5x5; lane = (row ry = l>>1, x-half xh = l&1) ----
  const int c = tid >> 5, l = tid & 31;
  v2h W01[5], W23[5], W12[5], W34[5];
  float W0s[5], W4s[5];
#pragma unroll
  for (int dy = 0; dy < 5; ++dy) {
    W01[dy] = *(const v2h*)&w_pairs[c][dy][0];
    W23[dy] = *(const v2h*)&w_pairs[c][dy][2];
    W12[dy] = *(const v2h*)&w_pairs[c][dy][4];
    W34[dy] = *(const v2h*)&w_pairs[c][dy][6];
    W0s[dy] = (float)W01[dy][0];
    W4s[dy] = (float)W34[dy][1];
  }
  const float bc = b_dw[c0 + c];

  float csum = 0.0f;
  if (l < 28) {
    const int ry = l >> 1;       // local output row 0..13
    const int bx = (l & 1) * 14; // x-half base
    // output row ry reads LDS rows ry..ry+4 = input rows (14h+ry)-2..+2
    v2h P0[5], P1[5], P2[5], P3[5];
#pragma unroll
    for (int dy = 0; dy < 5; ++dy) {
      const _Float16* row = &e_lds[c][ry + dy][bx];
      P0[dy] = *(const v2h*)(row + 4);    // pixels bx-2,bx-1
      P1[dy] = *(const v2h*)(row + 6);
      P2[dy] = *(const v2h*)(row + 8);
      P3[dy] = *(const v2h*)(row + 10);
    }
#pragma unroll
    for (int xi = 0; xi < 3; ++xi) {      // x0 = bx, bx+4, bx+8
      const int x0 = bx + xi * 4;
      float o0 = bc, o1 = bc, o2 = bc, o3 = bc;
#pragma unroll
      for (int dy = 0; dy < 5; ++dy) {
        o0 = fdot2(P0[dy], W01[dy], o0);
        o0 = fdot2(P1[dy], W23[dy], o0);
        o0 += (float)P2[dy][0] * W4s[dy];
        o1 += (float)P0[dy][1] * W0s[dy];
        o1 = fdot2(P1[dy], W12[dy], o1);
        o1 = fdot2(P2[dy], W34[dy], o1);
        o2 = fdot2(P1[dy], W01[dy], o2);
        o2 = fdot2(P2[dy], W23[dy], o2);
        o2 += (float)P3[dy][0] * W4s[dy];
        o3 += (float)P1[dy][1] * W0s[dy];
        o3 = fdot2(P2[dy], W12[dy], o3);
        o3 = fdot2(P3[dy], W34[dy], o3);
      }
      float oo[4] = {o0, o1, o2, o3};
      v2h dva, dvb;
#pragma unroll
      for (int i = 0; i < 4; ++i) {
        float deq = oo[i] * 4.0e-4f;            // S1 * W_SCALE
        float cl  = fminf(fmaxf(deq + 3.0f, 0.0f), 6.0f);
        float dvv = fminf(fmaxf(deq * cl * (25.0f / 6.0f), -128.0f), 127.0f); // d-128
        if (i < 2) dva[i] = (_Float16)dvv; else dvb[i - 2] = (_Float16)dvv;
        csum += dvv;
      }
      *(v2h*)&d_tile[c][ry * 28 + x0]     = dva;   // b32 stores, 4B-aligned
      *(v2h*)&d_tile[c][ry * 28 + x0 + 2] = dvb;
      // slide window (last slide reads halves up to 37 -> zeroed tail, in-row)
#pragma unroll
      for (int dy = 0; dy < 5; ++dy) {
        const _Float16* row = &e_lds[c][ry + dy][bx];
        P0[dy] = P2[dy];
        P1[dy] = P3[dy];
        P2[dy] = *(const v2h*)(row + x0 - bx + 12);
        P3[dy] = *(const v2h*)(row + x0 - bx + 14);
      }
    }
    {  // tail: x0 = bx+12, outputs o0,o1 only (P0,P1,P2 valid from slide)
      float o0 = bc, o1 = bc;
#pragma unroll
      for (int dy = 0; dy < 5; ++dy) {
        o0 = fdot2(P0[dy], W01[dy], o0);
        o0 = fdot2(P1[dy], W23[dy], o0);
        o0 += (float)P2[dy][0] * W4s[dy];
        o1 += (float)P0[dy][1] * W0s[dy];
        o1 = fdot2(P1[dy], W12[dy], o1);
        o1 = fdot2(P2[dy], W34[dy], o1);
      }
      v2h dv;
      float oo[2] = {o0, o1};
#pragma unroll
      for (int i = 0; i < 2; ++i) {
        float deq = oo[i] * 4.0e-4f;
        float cl  = fminf(fmaxf(deq + 3.0f, 0.0f), 6.0f);
        float dvv = fminf(fmaxf(deq * cl * (25.0f / 6.0f), -128.0f), 127.0f);
        dv[i] = (_Float16)dvv;
        csum += dvv;
      }
      *(v2h*)&d_tile[c][ry * 28 + bx + 12] = dv;
    }
  }
#pragma unroll
  for (int m = 16; m >= 1; m >>= 1) csum += __shfl_xor(csum, m);
  if (l == 0) d_sums2[((size_t)h * NB + n) * CE + c0 + c] = csum;

  __syncthreads();
  // ---- phase 3: k-packed writeout d_t[n][cg][hw][8], hw in [392h, 392h+392) ----
  const size_t obase = ((size_t)n * 72 + (c0 >> 3)) * 784 + 392 * h;
  if (tid < 392) {
    int hw_l = tid;
    v8h o0, o1;
#pragma unroll
    for (int j = 0; j < 8; ++j) { o0[j] = d_tile[j][hw_l]; o1[j] = d_tile[8 + j][hw_l]; }
    *(v8h*)&d_t[(obase + hw_l) * 8] = o0;
    *(v8h*)&d_t[(obase + 784 + hw_l) * 8] = o1;
  }
}

// ---------------- K3a: SE fc1 — one wave per (n, o); sums 2 pool partials -----
__global__ __launch_bounds__(256) void k3a_fc1(const float* __restrict__ d_sums2,
                                               const float* __restrict__ w_se1,
                                               const float* __restrict__ b_se1,
                                               float* __restrict__ g1) {
  const int tid = threadIdx.x;
  const int wv = tid >> 6, lane = tid & 63;
  const int n = blockIdx.y;
  const int o = blockIdx.x * 4 + wv;       // 144 outputs
  const float* wrow = &w_se1[o * CE];
  const float* s0 = &d_sums2[(size_t)n * CE];
  const float* s1 = &d_sums2[((size_t)NB + n) * CE];
  float p = 0.f;
#pragma unroll
  for (int s = 0; s < 9; ++s) {
    int cc = lane + s * 64;
    p += wrow[cc] * (s0[cc] + s1[cc]);
  }
#pragma unroll
  for (int m = 32; m >= 1; m >>= 1) p += __shfl_xor(p, m);
  if (lane == 0) {
    float deq = (p * (1.0f / 784.0f) + b_se1[o]) * 4.0e-4f;  // S2 * W_SCALE
    g1[n * SEC + o] = fminf(fmaxf(deq * 33.3333333f + 128.0f, 0.0f), 255.0f) - 128.0f;
  }
}

// ---------------- K3b: SE fc2 + hardsigmoid -> f16 gate table -----------------
__global__ __launch_bounds__(256) void k3b_fc2(const float* __restrict__ g1,
                                               const float* __restrict__ w_se2,
                                               const float* __restrict__ b_se2,
                                               _Float16* __restrict__ g2h) {
  const int tid = threadIdx.x;
  const int wv = tid >> 6, lane = tid & 63;
  const int n = blockIdx.y;
  const int o = blockIdx.x * 4 + wv;       // 576 outputs
  const float* wrow = &w_se2[o * SEC];
  const float* grow = &g1[n * SEC];
  float p = wrow[lane] * grow[lane] + wrow[lane + 64] * grow[lane + 64];
  if (lane < 16) p += wrow[lane + 128] * grow[lane + 128];
#pragma unroll
  for (int m = 32; m >= 1; m >>= 1) p += __shfl_xor(p, m);
  if (lane == 0) {
    float deq = (p + b_se2[o]) * 3.0e-4f;  // S_SE1 * W_SCALE
    g2h[n * CE + o] =
        (_Float16)(fminf(fmaxf(deq + 3.0f, 0.0f), 6.0f) * (1.0f / 6.0f)); // hardsigmoid
  }
}

// ---------------- K4: gated project 1x1 + residual add -> out fp32 -----------
// No LDS/barriers, 7 independent accumulators per wave for load ILP.
// Gate folded into the A fragment. M-split co-groups of 48 -> 896 blocks.
__global__ __launch_bounds__(192) void k4_proj(const _Float16* __restrict__ d_t,
                                               const _Float16* __restrict__ g2h,
                                               const _Float16* __restrict__ w_proj_h,
                                               const float* __restrict__ b_proj,
                                               const float* __restrict__ x,
                                               float* __restrict__ out) {
  const int tid = threadIdx.x;
  const int n = blockIdx.z;
  const int co0 = blockIdx.y * 48;
  const int hw0 = blockIdx.x * 112;
  const int wv = tid >> 6, lane = tid & 63;
  const int l15 = lane & 15, q = lane >> 4;

  v4f acc[7];
#pragma unroll
  for (int t = 0; t < 7; ++t) acc[t] = (v4f){0.f, 0.f, 0.f, 0.f};

  const _Float16* dbase = d_t + (((size_t)n * 72 + q) * 784 + hw0 + l15) * 8;
  const _Float16* abase = &w_proj_h[(co0 + wv * 16 + l15) * CE + q * 8];
  const _Float16* gbase = &g2h[(size_t)n * CE + q * 8];

  for (int ks = 0; ks < 18; ++ks) {
    v8h a = *(const v8h*)(abase + ks * 32);
    v8h g = *(const v8h*)(gbase + ks * 32);
    v8h ag = a * g;   // 4x v_pk_mul_f16, shared across the 7 MFMAs
    const _Float16* dk = dbase + (size_t)ks * (4 * 784 * 8);
#pragma unroll
    for (int t = 0; t < 7; ++t) {
      v8h b = *(const v8h*)(dk + t * (16 * 8));
      acc[t] = __builtin_amdgcn_mfma_f32_16x16x32_f16(ag, b, acc[t], 0, 0, 0);
    }
  }

  float bia[4];
#pragma unroll
  for (int r = 0; r < 4; ++r) bia[r] = b_proj[co0 + wv * 16 + q * 4 + r];

#pragma unroll
  for (int t = 0; t < 7; ++t) {
#pragma unroll
    for (int r = 0; r < 4; ++r) {
      int co = co0 + wv * 16 + q * 4 + r;
      int hw = hw0 + t * 16 + l15;
      float p = fminf(fmaxf((acc[t][r] + bia[r]) * 4.0e-4f * 20.0f + 128.0f, 0.0f), 255.0f);
      float xv = x[(n * CO + co) * HW + hw];
      float o = (xv - 128.0f) * 0.8333333333f + (p - 128.0f) * 0.8333333333f + 128.0f;
      out[(n * CO + co) * HW + hw] = fminf(fmaxf(o, 0.0f), 255.0f);
    }
  }
}

extern "C" void kernel_launch(void* const* d_in, const int* in_sizes, int n_in,
                              void* d_out, int out_size, void* d_ws, size_t ws_size,
                              hipStream_t stream) {
  const float* x      = (const float*)d_in[0];
  const float* w_exp  = (const float*)d_in[1];
  const float* b_exp  = (const float*)d_in[2];
  const float* w_dw   = (const float*)d_in[3];
  const float* b_dw   = (const float*)d_in[4];
  const float* w_se1  = (const float*)d_in[5];
  const float* b_se1  = (const float*)d_in[6];
  const float* w_se2  = (const float*)d_in[7];
  const float* b_se2  = (const float*)d_in[8];
  const float* w_proj = (const float*)d_in[9];
  const float* b_proj = (const float*)d_in[10];
  float* out = (float*)d_out;

  char* ws = (char*)d_ws;
  const size_t SZ_W  = (size_t)CE * CI * 2;            // 110592 B
  const size_t SZ_XF = (size_t)NB * 49 * 3 * 512 * 2;  // 9633792 B
  const size_t SZ_D  = (size_t)NB * CE * HW * 2;       // 57802752 B
  const size_t SZ_S2 = (size_t)2 * NB * CE * 4;        // 294912 B
  const size_t SZ_S  = (size_t)NB * CE * 4;            // 147456 B
  _Float16* w_exp_h  = (_Float16*)(ws);
  _Float16* w_proj_h = (_Float16*)(ws + SZ_W);
  _Float16* x_f      = (_Float16*)(ws + 2 * SZ_W);
  _Float16* d_t      = (_Float16*)(ws + 2 * SZ_W + SZ_XF);    // [n][72][784][8]
  float*    d_sums2  = (float*)   (ws + 2 * SZ_W + SZ_XF + SZ_D);
  float*    g1       = (float*)   (ws + 2 * SZ_W + SZ_XF + SZ_D + SZ_S2);
  _Float16* g2h      = (_Float16*)(ws + 2 * SZ_W + SZ_XF + SZ_D + SZ_S2 + SZ_S);
  // total ws use: ~68 MB

  k0_cvt_w<<<(CE * CI + 255) / 256, 256, 0, stream>>>(w_exp, w_proj, w_exp_h, w_proj_h);
  k0x_pack<<<dim3(7, NB), 256, 0, stream>>>(x, x_f);
  k12_fused<<<dim3(36, 2, NB), 512, 0, stream>>>(x_f, w_exp_h, b_exp, w_dw, b_dw, d_t, d_sums2);
  k3a_fc1<<<dim3(36, NB), 256, 0, stream>>>(d_sums2, w_se1, b_se1, g1);
  k3b_fc2<<<dim3(144, NB), 256, 0, stream>>>(g1, w_se2, b_se2, g2h);
  k4_proj<<<dim3(7, 2, NB), 192, 0, stream>>>(d_t, g2h, w_proj_h, b_proj, x, out);
}